// Round 1
// baseline (2131.672 us; speedup 1.0000x reference)
//
#include <hip/hip_runtime.h>
#include <hip/hip_bf16.h>
#include <math.h>

// Problem constants
constexpr int B = 8, S = 512, T = 256, D = 768, H = 12, HID = 3072;
constexpr int V = 50257, O = 64, HD = 64;

// ---------------------------------------------------------------------------
// Generic tiled fp32 GEMM: C[M,N] = A[M,K] @ W[N,K]^T + bias[N], optional ReLU
// 64x64 block tile, 16 k-tile, 256 threads, 4x4 per-thread microtile.
// ---------------------------------------------------------------------------
template <bool RELU>
__global__ void gemm_bias_kernel(const float* __restrict__ A,
                                 const float* __restrict__ W,
                                 const float* __restrict__ bias,
                                 float* __restrict__ C,
                                 int M, int N, int K) {
  __shared__ float As[64][17];   // +1 pad: rows stride 17 -> no bank conflict
  __shared__ float Ws[16][65];   // Ws[k][n]
  const int tx = threadIdx.x & 15;
  const int ty = threadIdx.x >> 4;
  const int row0 = blockIdx.y * 64;
  const int col0 = blockIdx.x * 64;

  float acc[4][4] = {};

  for (int k0 = 0; k0 < K; k0 += 16) {
    // Load A tile (64 rows x 16 k)
    for (int i = threadIdx.x; i < 64 * 16; i += 256) {
      int r = i >> 4, c = i & 15;
      int gr = row0 + r;
      As[r][c] = (gr < M) ? A[(size_t)gr * K + (k0 + c)] : 0.f;
    }
    // Load W tile (64 n-rows x 16 k), transposed into Ws[k][n]
    for (int i = threadIdx.x; i < 64 * 16; i += 256) {
      int n = i >> 4, c = i & 15;
      int gn = col0 + n;
      Ws[c][n] = (gn < N) ? W[(size_t)gn * K + (k0 + c)] : 0.f;
    }
    __syncthreads();
#pragma unroll
    for (int kk = 0; kk < 16; ++kk) {
      float a[4], b[4];
#pragma unroll
      for (int i = 0; i < 4; ++i) a[i] = As[ty * 4 + i][kk];
#pragma unroll
      for (int j = 0; j < 4; ++j) b[j] = Ws[kk][tx * 4 + j];
#pragma unroll
      for (int i = 0; i < 4; ++i)
#pragma unroll
        for (int j = 0; j < 4; ++j) acc[i][j] += a[i] * b[j];
    }
    __syncthreads();
  }

#pragma unroll
  for (int i = 0; i < 4; ++i) {
    int r = row0 + ty * 4 + i;
    if (r >= M) continue;
#pragma unroll
    for (int j = 0; j < 4; ++j) {
      int c = col0 + tx * 4 + j;
      if (c < N) {
        float vv = acc[i][j] + bias[c];
        if (RELU) vv = fmaxf(vv, 0.f);
        C[(size_t)r * N + c] = vv;
      }
    }
  }
}

// ---------------------------------------------------------------------------
// Row softmax over O=64 (one wave per row)
// ---------------------------------------------------------------------------
__global__ void softmax64_kernel(const float* __restrict__ logits,
                                 float* __restrict__ probs, int rows) {
  int row = blockIdx.x * (blockDim.x >> 6) + (threadIdx.x >> 6);
  int lane = threadIdx.x & 63;
  if (row >= rows) return;
  float x = logits[(size_t)row * 64 + lane];
  float m = x;
#pragma unroll
  for (int o = 32; o > 0; o >>= 1) m = fmaxf(m, __shfl_xor(m, o));
  float e = __expf(x - m);
  float ssum = e;
#pragma unroll
  for (int o = 32; o > 0; o >>= 1) ssum += __shfl_xor(ssum, o);
  probs[(size_t)row * 64 + lane] = e / ssum;
}

// ---------------------------------------------------------------------------
// Attention: one block (256 thr) per (b,h,t). Computes scores, softmax,
// context; accumulates head-mean attn into fs[B,T,S] via atomics.
// ---------------------------------------------------------------------------
__global__ void attention_kernel(const float* __restrict__ q,
                                 const float* __restrict__ k,
                                 const float* __restrict__ v,
                                 const unsigned char* __restrict__ mask,
                                 float* __restrict__ ctx,
                                 float* __restrict__ fs) {
  const int bid = blockIdx.x;
  const int t = bid % T;
  const int h = (bid / T) % H;
  const int b = bid / (T * H);
  const int tid = threadIdx.x;

  __shared__ float qs[64];
  __shared__ float sc[512];
  __shared__ float red[256];

  if (tid < 64) qs[tid] = q[((size_t)(b * T + t)) * D + h * 64 + tid];
  __syncthreads();

  // scores: each thread handles s = tid and s = tid+256
  float l0, l1;
  {
    const float* kp = &k[((size_t)(b * S + tid)) * D + h * 64];
    float acc = 0.f;
#pragma unroll 16
    for (int d = 0; d < 64; ++d) acc += qs[d] * kp[d];
    acc *= 0.125f;
    if (mask[b * S + tid]) acc = -INFINITY;
    sc[tid] = acc;
    l0 = acc;
  }
  {
    int s = tid + 256;
    const float* kp = &k[((size_t)(b * S + s)) * D + h * 64];
    float acc = 0.f;
#pragma unroll 16
    for (int d = 0; d < 64; ++d) acc += qs[d] * kp[d];
    acc *= 0.125f;
    if (mask[b * S + s]) acc = -INFINITY;
    sc[s] = acc;
    l1 = acc;
  }

  // block max
  red[tid] = fmaxf(l0, l1);
  __syncthreads();
  for (int st = 128; st > 0; st >>= 1) {
    if (tid < st) red[tid] = fmaxf(red[tid], red[tid + st]);
    __syncthreads();
  }
  float m = red[0];
  __syncthreads();

  float e0 = __expf(l0 - m);
  float e1 = __expf(l1 - m);
  red[tid] = e0 + e1;
  __syncthreads();
  for (int st = 128; st > 0; st >>= 1) {
    if (tid < st) red[tid] += red[tid + st];
    __syncthreads();
  }
  float inv = 1.f / red[0];
  __syncthreads();  // before reusing red

  float a0 = e0 * inv, a1 = e1 * inv;
  sc[tid] = a0;
  sc[tid + 256] = a1;
  const float invH = 1.0f / (float)H;
  atomicAdd(&fs[((size_t)(b * T + t)) * S + tid], a0 * invH);
  atomicAdd(&fs[((size_t)(b * T + t)) * S + tid + 256], a1 * invH);
  __syncthreads();

  // ctx[d] = sum_s attn[s] * v[b,s,h,d]; 4 groups of 64 threads
  const int d = tid & 63;
  const int g = tid >> 6;
  float acc = 0.f;
  for (int s = g * 128; s < (g + 1) * 128; ++s)
    acc += sc[s] * v[((size_t)(b * S + s)) * D + h * 64 + d];
  red[tid] = acc;
  __syncthreads();
  if (tid < 64) {
    float r = red[tid] + red[tid + 64] + red[tid + 128] + red[tid + 192];
    ctx[((size_t)(b * T + t)) * D + h * 64 + tid] = r;
  }
}

// ---------------------------------------------------------------------------
// Copy head: sigmoid(context_out @ copy_w + copy_b), one wave per row
// ---------------------------------------------------------------------------
__global__ void copy_head_kernel(const float* __restrict__ co,
                                 const float* __restrict__ w,
                                 const float* __restrict__ bptr,
                                 float* __restrict__ cp, int rows) {
  int row = blockIdx.x * (blockDim.x >> 6) + (threadIdx.x >> 6);
  int lane = threadIdx.x & 63;
  if (row >= rows) return;
  float acc = 0.f;
#pragma unroll
  for (int d = lane; d < D; d += 64) acc += co[(size_t)row * D + d] * w[d];
#pragma unroll
  for (int o = 32; o > 0; o >>= 1) acc += __shfl_xor(acc, o);
  if (lane == 0) cp[row] = 1.f / (1.f + __expf(-(acc + bptr[0])));
}

// ---------------------------------------------------------------------------
// Scatter: out zeroed beforehand. First B*T*S threads add source probs,
// next B*T*O threads add ontology probs.
// ---------------------------------------------------------------------------
__global__ void scatter_kernel(const int* __restrict__ src,
                               const int* __restrict__ onto,
                               const float* __restrict__ fs,
                               const float* __restrict__ op,
                               const float* __restrict__ cp,
                               float* __restrict__ out) {
  long long i = (long long)blockIdx.x * blockDim.x + threadIdx.x;
  const long long nsrc = (long long)B * T * S;
  const long long nonto = (long long)B * T * O;
  if (i < nsrc) {
    int s = (int)(i % S);
    long long bt = i / S;
    int b = (int)(bt / T);
    float val = fs[i] * cp[bt];
    atomicAdd(&out[bt * V + src[b * S + s]], val);
  } else if (i < nsrc + nonto) {
    long long j = i - nsrc;
    int o = (int)(j % O);
    long long bt = j / O;
    float val = op[j] * (1.f - cp[bt]);
    atomicAdd(&out[bt * V + onto[o]], val);
  }
}

// ---------------------------------------------------------------------------
extern "C" void kernel_launch(void* const* d_in, const int* in_sizes, int n_in,
                              void* d_out, int out_size, void* d_ws, size_t ws_size,
                              hipStream_t stream) {
  const int* src_ids = (const int*)d_in[0];
  const float* enc = (const float*)d_in[1];
  const unsigned char* mask = (const unsigned char*)d_in[2];
  const float* dec = (const float*)d_in[3];
  const int* onto_ids = (const int*)d_in[4];
  const float* Wq = (const float*)d_in[5];
  const float* bq = (const float*)d_in[6];
  const float* Wk = (const float*)d_in[7];
  const float* bk = (const float*)d_in[8];
  const float* Wv = (const float*)d_in[9];
  const float* bv = (const float*)d_in[10];
  const float* Wo = (const float*)d_in[11];
  const float* bo = (const float*)d_in[12];
  const float* copy_w = (const float*)d_in[13];
  const float* copy_b = (const float*)d_in[14];
  const float* W1 = (const float*)d_in[15];
  const float* b1 = (const float*)d_in[16];
  const float* W2 = (const float*)d_in[17];
  const float* b2 = (const float*)d_in[18];

  float* ws = (float*)d_ws;
  const int MT = B * T;      // 2048 decoder rows
  const int MS = B * S;      // 4096 encoder rows

  float* qb = ws;                       // [MT, D]
  float* kb = qb + (size_t)MT * D;      // [MS, D]
  float* vb = kb + (size_t)MS * D;      // [MS, D]
  float* hb = vb + (size_t)MS * D;      // [MT, HID]
  float* logits = hb + (size_t)MT * HID;   // [MT, O]
  float* ontop = logits + (size_t)MT * O;  // [MT, O]
  float* ctxb = ontop + (size_t)MT * O;    // [MT, D]
  float* ctxout = ctxb + (size_t)MT * D;   // [MT, D]
  float* cp = ctxout + (size_t)MT * D;     // [MT]
  float* fsb = cp + (size_t)MT;            // [MT, S]

  float* out = (float*)d_out;

  // Zero the output (reference starts from zeros) and the from_source acc.
  hipMemsetAsync(out, 0, (size_t)B * T * V * sizeof(float), stream);
  hipMemsetAsync(fsb, 0, (size_t)MT * S * sizeof(float), stream);

  dim3 blk(256);

  // Projections
  gemm_bias_kernel<false><<<dim3(D / 64, MT / 64), blk, 0, stream>>>(dec, Wq, bq, qb, MT, D, D);
  gemm_bias_kernel<false><<<dim3(D / 64, MS / 64), blk, 0, stream>>>(enc, Wk, bk, kb, MS, D, D);
  gemm_bias_kernel<false><<<dim3(D / 64, MS / 64), blk, 0, stream>>>(enc, Wv, bv, vb, MS, D, D);

  // Generator FFN
  gemm_bias_kernel<true><<<dim3(HID / 64, MT / 64), blk, 0, stream>>>(dec, W1, b1, hb, MT, HID, D);
  gemm_bias_kernel<false><<<dim3(1, MT / 64), blk, 0, stream>>>(hb, W2, b2, logits, MT, O, HID);
  softmax64_kernel<<<MT / 4, 256, 0, stream>>>(logits, ontop, MT);

  // Attention
  attention_kernel<<<B * H * T, 256, 0, stream>>>(qb, kb, vb, mask, ctxb, fsb);

  // Output projection + copy head
  gemm_bias_kernel<false><<<dim3(D / 64, MT / 64), blk, 0, stream>>>(ctxb, Wo, bo, ctxout, MT, D, D);
  copy_head_kernel<<<MT / 4, 256, 0, stream>>>(ctxout, copy_w, copy_b, cp, MT);

  // Scatter into vocab distribution
  long long total = (long long)B * T * (S + O);
  int nblk = (int)((total + 255) / 256);
  scatter_kernel<<<nblk, 256, 0, stream>>>(src_ids, onto_ids, fsb, ontop, cp, out);
}

// Round 2
// 589.911 us; speedup vs baseline: 3.6135x; 3.6135x over previous
//
#include <hip/hip_runtime.h>
#include <hip/hip_bf16.h>
#include <math.h>

// Problem constants
constexpr int B = 8, S = 512, T = 256, D = 768, H = 12, HID = 3072;
constexpr int V = 50257, O = 64, HD = 64;

typedef short bf16x8 __attribute__((ext_vector_type(8)));
typedef float f32x4 __attribute__((ext_vector_type(4)));

__device__ __forceinline__ float b2f(unsigned short u) {
  union { float f; unsigned v; } x; x.v = ((unsigned)u) << 16; return x.f;
}
__device__ __forceinline__ unsigned short f2b(float f) {
  __hip_bfloat16 h = __float2bfloat16(f);
  return *(unsigned short*)&h;
}

__device__ __forceinline__ void async16(const void* g, void* l) {
  __builtin_amdgcn_global_load_lds(
      (const __attribute__((address_space(1))) void*)g,
      (__attribute__((address_space(3))) void*)l, 16, 0, 0);
}

// ---------------------------------------------------------------------------
// fp32 -> bf16 conversion (8 elems/thread, n % 8 == 0)
// ---------------------------------------------------------------------------
__global__ void cvt_f32_bf16(const float* __restrict__ in,
                             __hip_bfloat16* __restrict__ out, int n) {
  int i = (blockIdx.x * blockDim.x + threadIdx.x) * 8;
  if (i + 8 > n) return;
  float4 v0 = *(const float4*)&in[i];
  float4 v1 = *(const float4*)&in[i + 4];
  ushort4 o0, o1;
  o0.x = f2b(v0.x); o0.y = f2b(v0.y); o0.z = f2b(v0.z); o0.w = f2b(v0.w);
  o1.x = f2b(v1.x); o1.y = f2b(v1.y); o1.z = f2b(v1.z); o1.w = f2b(v1.w);
  *(ushort4*)&out[i] = o0;
  *(ushort4*)&out[i + 4] = o1;
}

// ---------------------------------------------------------------------------
// bf16 MFMA GEMM: C[M,N] = A[M,K] @ W[N,K]^T + bias, optional ReLU.
// BM=128, BN in {64,128}, BK=32. 256 threads = 4 waves (2x2), wave tile
// 64 x BN/2, 16x16x32 bf16 MFMA, fp32 accum. M%128==0, N%BN==0, K%32==0.
// Outputs: Cf (fp32) and/or Cb (bf16) — pass nullptr to skip.
// ---------------------------------------------------------------------------
template <int BN, bool RELU>
__global__ __launch_bounds__(256) void gemm_mfma_kernel(
    const __hip_bfloat16* __restrict__ A, const __hip_bfloat16* __restrict__ W,
    const float* __restrict__ bias, float* __restrict__ Cf,
    __hip_bfloat16* __restrict__ Cb, int M, int N, int K) {
  constexpr int BM = 128, BK = 32;
  constexpr int WTN = BN / 2;      // wave tile N: 64 or 32
  constexpr int NFRAG = WTN / 16;  // 4 or 2
  __shared__ __hip_bfloat16 Als[BM * BK];
  __shared__ __hip_bfloat16 Bls[BN * BK];
  const int tid = threadIdx.x;
  const int lane = tid & 63, wid = tid >> 6;
  const int wm = wid >> 1, wn = wid & 1;
  const int row0 = blockIdx.y * BM, col0 = blockIdx.x * BN;
  const int lr = lane & 15;          // frag row/col
  const int ko = (lane >> 4) * 8;    // frag k offset (elems)

  f32x4 acc[4][NFRAG] = {};

  for (int k0 = 0; k0 < K; k0 += BK) {
    // stage A tile: 128x32 bf16 = 8 KB = 512 chunks of 16 B (2/thread)
#pragma unroll
    for (int c = 0; c < 2; ++c) {
      int j = tid + c * 256;
      int r = j >> 2, col = (j & 3) * 8;
      async16(&A[(size_t)(row0 + r) * K + k0 + col], (void*)&Als[j * 8]);
    }
    // stage B tile: BN x 32
#pragma unroll
    for (int c = 0; c < BN / 64; ++c) {
      int j = tid + c * 256;
      int r = j >> 2, col = (j & 3) * 8;
      async16(&W[(size_t)(col0 + r) * K + k0 + col], (void*)&Bls[j * 8]);
    }
    __syncthreads();  // drains vmcnt before LDS reads

    bf16x8 af[4], bfr[NFRAG];
#pragma unroll
    for (int mi = 0; mi < 4; ++mi)
      af[mi] = *(const bf16x8*)&Als[(wm * 64 + mi * 16 + lr) * BK + ko];
#pragma unroll
    for (int ni = 0; ni < NFRAG; ++ni)
      bfr[ni] = *(const bf16x8*)&Bls[(wn * WTN + ni * 16 + lr) * BK + ko];
#pragma unroll
    for (int mi = 0; mi < 4; ++mi)
#pragma unroll
      for (int ni = 0; ni < NFRAG; ++ni)
        acc[mi][ni] = __builtin_amdgcn_mfma_f32_16x16x32_bf16(
            af[mi], bfr[ni], acc[mi][ni], 0, 0, 0);
    __syncthreads();
  }

  // epilogue: D col = lane&15, row = (lane>>4)*4 + reg
#pragma unroll
  for (int mi = 0; mi < 4; ++mi) {
    int rbase = row0 + wm * 64 + mi * 16 + (lane >> 4) * 4;
#pragma unroll
    for (int ni = 0; ni < NFRAG; ++ni) {
      int c = col0 + wn * WTN + ni * 16 + lr;
      float bv = bias[c];
#pragma unroll
      for (int r = 0; r < 4; ++r) {
        float val = acc[mi][ni][r] + bv;
        if (RELU) val = fmaxf(val, 0.f);
        if (Cf) Cf[(size_t)(rbase + r) * N + c] = val;
        if (Cb) Cb[(size_t)(rbase + r) * N + c] = __float2bfloat16(val);
      }
    }
  }
}

// ---------------------------------------------------------------------------
// Row softmax over O=64 (one wave per row)
// ---------------------------------------------------------------------------
__global__ void softmax64_kernel(const float* __restrict__ logits,
                                 float* __restrict__ probs, int rows) {
  int row = blockIdx.x * (blockDim.x >> 6) + (threadIdx.x >> 6);
  int lane = threadIdx.x & 63;
  if (row >= rows) return;
  float x = logits[(size_t)row * 64 + lane];
  float m = x;
#pragma unroll
  for (int o = 32; o > 0; o >>= 1) m = fmaxf(m, __shfl_xor(m, o));
  float e = __expf(x - m);
  float ssum = e;
#pragma unroll
  for (int o = 32; o > 0; o >>= 1) ssum += __shfl_xor(ssum, o);
  probs[(size_t)row * 64 + lane] = e / ssum;
}

// ---------------------------------------------------------------------------
// Attention v2: one block per (b, h, tile of 16 t). bf16 q/k/v inputs,
// fp32 LDS compute, scores materialized in LDS (needed for head-mean),
// wave-parallel softmax, register-blocked PV. Writes bf16 ctx + fp32 fs.
// ---------------------------------------------------------------------------
__global__ __launch_bounds__(256) void attention2_kernel(
    const __hip_bfloat16* __restrict__ q, const __hip_bfloat16* __restrict__ k,
    const __hip_bfloat16* __restrict__ v, const unsigned char* __restrict__ mask,
    __hip_bfloat16* __restrict__ ctx, float* __restrict__ fs) {
  constexpr int TB = 16;
  __shared__ float qs[TB][72];    // pad 72: 16B-aligned rows, spread banks
  __shared__ float ks[32][72];
  __shared__ float sc[TB][520];   // pad 520: PV broadcast across banks
  const int bid = blockIdx.x;
  const int tile = bid & 15;              // T/TB = 16 tiles
  const int h = (bid >> 4) % H;
  const int b = bid / (16 * H);
  const int t0 = tile * TB;
  const int tid = threadIdx.x;

  // load q tile: 16 x 64 bf16 -> fp32 LDS
  if (tid < 128) {
    int r = tid >> 3, c8 = (tid & 7) * 8;
    const unsigned short* qp =
        (const unsigned short*)&q[((size_t)(b * T + t0 + r)) * D + h * 64 + c8];
    ushort4 u0 = *(const ushort4*)qp;
    ushort4 u1 = *(const ushort4*)(qp + 4);
    qs[r][c8 + 0] = b2f(u0.x); qs[r][c8 + 1] = b2f(u0.y);
    qs[r][c8 + 2] = b2f(u0.z); qs[r][c8 + 3] = b2f(u0.w);
    qs[r][c8 + 4] = b2f(u1.x); qs[r][c8 + 5] = b2f(u1.y);
    qs[r][c8 + 6] = b2f(u1.z); qs[r][c8 + 7] = b2f(u1.w);
  }
  __syncthreads();

  // ---- scores: 16 chunks of 32 s ----
  for (int ch = 0; ch < 16; ++ch) {
    int s0 = ch * 32;
    {
      int r = tid >> 3, c8 = (tid & 7) * 8;
      const unsigned short* kp =
          (const unsigned short*)&k[((size_t)(b * S + s0 + r)) * D + h * 64 + c8];
      ushort4 u0 = *(const ushort4*)kp;
      ushort4 u1 = *(const ushort4*)(kp + 4);
      ks[r][c8 + 0] = b2f(u0.x); ks[r][c8 + 1] = b2f(u0.y);
      ks[r][c8 + 2] = b2f(u0.z); ks[r][c8 + 3] = b2f(u0.w);
      ks[r][c8 + 4] = b2f(u1.x); ks[r][c8 + 5] = b2f(u1.y);
      ks[r][c8 + 6] = b2f(u1.z); ks[r][c8 + 7] = b2f(u1.w);
    }
    __syncthreads();
#pragma unroll
    for (int pp = 0; pp < 2; ++pp) {
      int p = tid + pp * 256;
      int tt = p & 15, ss = p >> 4;
      float a = 0.f;
#pragma unroll
      for (int d4 = 0; d4 < 16; ++d4) {
        float4 qv = *(const float4*)&qs[tt][d4 * 4];
        float4 kv = *(const float4*)&ks[ss][d4 * 4];
        a += qv.x * kv.x + qv.y * kv.y + qv.z * kv.z + qv.w * kv.w;
      }
      a *= 0.125f;
      int s = s0 + ss;
      if (mask[b * S + s]) a = -INFINITY;
      sc[tt][s] = a;
    }
    __syncthreads();
  }

  // ---- softmax: wave w handles rows w*4 .. w*4+3 ----
  const int lane = tid & 63, w = tid >> 6;
  const float invH = 1.0f / (float)H;
#pragma unroll
  for (int i = 0; i < 4; ++i) {
    int r = w * 4 + i;
    float x[8];
    float m = -INFINITY;
#pragma unroll
    for (int j = 0; j < 8; ++j) {
      x[j] = sc[r][j * 64 + lane];
      m = fmaxf(m, x[j]);
    }
#pragma unroll
    for (int o = 32; o > 0; o >>= 1) m = fmaxf(m, __shfl_xor(m, o));
    float ssum = 0.f;
#pragma unroll
    for (int j = 0; j < 8; ++j) { x[j] = __expf(x[j] - m); ssum += x[j]; }
#pragma unroll
    for (int o = 32; o > 0; o >>= 1) ssum += __shfl_xor(ssum, o);
    float inv = 1.f / ssum;
#pragma unroll
    for (int j = 0; j < 8; ++j) {
      float aw = x[j] * inv;
      sc[r][j * 64 + lane] = aw;
      atomicAdd(&fs[((size_t)(b * T + t0 + r)) * S + j * 64 + lane], aw * invH);
    }
  }
  __syncthreads();

  // ---- PV: thread (t = tid>>4, d4 = (tid&15)*4) ----
  {
    int t = tid >> 4, d4 = (tid & 15) * 4;
    float a0 = 0, a1 = 0, a2 = 0, a3 = 0;
    const unsigned short* vbase =
        (const unsigned short*)&v[((size_t)(b * S)) * D + h * 64 + d4];
    for (int s = 0; s < S; ++s) {
      float p = sc[t][s];
      ushort4 u = *(const ushort4*)(vbase + (size_t)s * D);
      a0 += p * b2f(u.x); a1 += p * b2f(u.y);
      a2 += p * b2f(u.z); a3 += p * b2f(u.w);
    }
    ushort4 o;
    o.x = f2b(a0); o.y = f2b(a1); o.z = f2b(a2); o.w = f2b(a3);
    *(ushort4*)&ctx[((size_t)(b * T + t0 + t)) * D + h * 64 + d4] = o;
  }
}

// ---------------------------------------------------------------------------
// Copy head: sigmoid(context_out @ copy_w + copy_b), one wave per row
// ---------------------------------------------------------------------------
__global__ void copy_head_kernel(const float* __restrict__ co,
                                 const float* __restrict__ w,
                                 const float* __restrict__ bptr,
                                 float* __restrict__ cp, int rows) {
  int row = blockIdx.x * (blockDim.x >> 6) + (threadIdx.x >> 6);
  int lane = threadIdx.x & 63;
  if (row >= rows) return;
  float acc = 0.f;
#pragma unroll
  for (int d = lane; d < D; d += 64) acc += co[(size_t)row * D + d] * w[d];
#pragma unroll
  for (int o = 32; o > 0; o >>= 1) acc += __shfl_xor(acc, o);
  if (lane == 0) cp[row] = 1.f / (1.f + __expf(-(acc + bptr[0])));
}

// ---------------------------------------------------------------------------
// Scatter into vocab distribution (out pre-zeroed)
// ---------------------------------------------------------------------------
__global__ void scatter_kernel(const int* __restrict__ src,
                               const int* __restrict__ onto,
                               const float* __restrict__ fs,
                               const float* __restrict__ op,
                               const float* __restrict__ cp,
                               float* __restrict__ out) {
  long long i = (long long)blockIdx.x * blockDim.x + threadIdx.x;
  const long long nsrc = (long long)B * T * S;
  const long long nonto = (long long)B * T * O;
  if (i < nsrc) {
    int s = (int)(i % S);
    long long bt = i / S;
    int b = (int)(bt / T);
    float val = fs[i] * cp[bt];
    atomicAdd(&out[bt * V + src[b * S + s]], val);
  } else if (i < nsrc + nonto) {
    long long j = i - nsrc;
    int o = (int)(j % O);
    long long bt = j / O;
    float val = op[j] * (1.f - cp[bt]);
    atomicAdd(&out[bt * V + onto[o]], val);
  }
}

// ---------------------------------------------------------------------------
extern "C" void kernel_launch(void* const* d_in, const int* in_sizes, int n_in,
                              void* d_out, int out_size, void* d_ws, size_t ws_size,
                              hipStream_t stream) {
  const int* src_ids = (const int*)d_in[0];
  const float* enc = (const float*)d_in[1];
  const unsigned char* mask = (const unsigned char*)d_in[2];
  const float* dec = (const float*)d_in[3];
  const int* onto_ids = (const int*)d_in[4];
  const float* Wq = (const float*)d_in[5];
  const float* bq = (const float*)d_in[6];
  const float* Wk = (const float*)d_in[7];
  const float* bk = (const float*)d_in[8];
  const float* Wv = (const float*)d_in[9];
  const float* bv = (const float*)d_in[10];
  const float* Wo = (const float*)d_in[11];
  const float* bo = (const float*)d_in[12];
  const float* copy_w = (const float*)d_in[13];
  const float* copy_b = (const float*)d_in[14];
  const float* W1 = (const float*)d_in[15];
  const float* b1 = (const float*)d_in[16];
  const float* W2 = (const float*)d_in[17];
  const float* b2 = (const float*)d_in[18];

  const int MT = B * T;   // 2048
  const int MS = B * S;   // 4096

  // bf16 workspace region
  __hip_bfloat16* wb = (__hip_bfloat16*)d_ws;
  __hip_bfloat16* qb16 = wb;                        wb += (size_t)MT * D;
  __hip_bfloat16* kb16 = wb;                        wb += (size_t)MS * D;
  __hip_bfloat16* vb16 = wb;                        wb += (size_t)MS * D;
  __hip_bfloat16* hb16 = wb;                        wb += (size_t)MT * HID;
  __hip_bfloat16* ctxb16 = wb;                      wb += (size_t)MT * D;
  __hip_bfloat16* decb = wb;                        wb += (size_t)MT * D;
  __hip_bfloat16* encb = wb;                        wb += (size_t)MS * D;
  __hip_bfloat16* W1b = wb;                         wb += (size_t)HID * D;
  __hip_bfloat16* W2b = wb;                         wb += (size_t)O * HID;
  __hip_bfloat16* Wqb = wb;                         wb += (size_t)D * D;
  __hip_bfloat16* Wkb = wb;                         wb += (size_t)D * D;
  __hip_bfloat16* Wvb = wb;                         wb += (size_t)D * D;
  __hip_bfloat16* Wob = wb;                         wb += (size_t)D * D;
  // fp32 workspace region
  float* wf = (float*)wb;
  float* logits = wf;                               wf += (size_t)MT * O;
  float* ontop = wf;                                wf += (size_t)MT * O;
  float* ctxout = wf;                               wf += (size_t)MT * D;
  float* cp = wf;                                   wf += (size_t)MT;
  float* fsb = wf;                                  wf += (size_t)MT * S;

  float* out = (float*)d_out;

  hipMemsetAsync(out, 0, (size_t)B * T * V * sizeof(float), stream);
  hipMemsetAsync(fsb, 0, (size_t)MT * S * sizeof(float), stream);

  // fp32 -> bf16 conversions
  auto cvt = [&](const float* s, __hip_bfloat16* dst, int n) {
    cvt_f32_bf16<<<(n / 8 + 255) / 256, 256, 0, stream>>>(s, dst, n);
  };
  cvt(dec, decb, MT * D);
  cvt(enc, encb, MS * D);
  cvt(W1, W1b, HID * D);
  cvt(W2, W2b, O * HID);
  cvt(Wq, Wqb, D * D);
  cvt(Wk, Wkb, D * D);
  cvt(Wv, Wvb, D * D);
  cvt(Wo, Wob, D * D);

  // Projections (bf16 out for attention)
  gemm_mfma_kernel<128, false><<<dim3(D / 128, MT / 128), 256, 0, stream>>>(
      decb, Wqb, bq, nullptr, qb16, MT, D, D);
  gemm_mfma_kernel<128, false><<<dim3(D / 128, MS / 128), 256, 0, stream>>>(
      encb, Wkb, bk, nullptr, kb16, MS, D, D);
  gemm_mfma_kernel<128, false><<<dim3(D / 128, MS / 128), 256, 0, stream>>>(
      encb, Wvb, bv, nullptr, vb16, MS, D, D);

  // Generator FFN
  gemm_mfma_kernel<128, true><<<dim3(HID / 128, MT / 128), 256, 0, stream>>>(
      decb, W1b, b1, nullptr, hb16, MT, HID, D);
  gemm_mfma_kernel<64, false><<<dim3(1, MT / 128), 256, 0, stream>>>(
      hb16, W2b, b2, logits, nullptr, MT, O, HID);
  softmax64_kernel<<<MT / 4, 256, 0, stream>>>(logits, ontop, MT);

  // Attention
  attention2_kernel<<<B * H * (T / 16), 256, 0, stream>>>(
      qb16, kb16, vb16, mask, ctxb16, fsb);

  // Output projection + copy head
  gemm_mfma_kernel<128, false><<<dim3(D / 128, MT / 128), 256, 0, stream>>>(
      ctxb16, Wob, bo, ctxout, nullptr, MT, D, D);
  copy_head_kernel<<<MT / 4, 256, 0, stream>>>(ctxout, copy_w, copy_b, cp, MT);

  // Scatter
  long long total = (long long)B * T * (S + O);
  int nblk = (int)((total + 255) / 256);
  scatter_kernel<<<nblk, 256, 0, stream>>>(src_ids, onto_ids, fsb, ontop, cp, out);
}

// Round 3
// 362.606 us; speedup vs baseline: 5.8788x; 1.6269x over previous
//
#include <hip/hip_runtime.h>
#include <hip/hip_bf16.h>
#include <math.h>

// Problem constants
constexpr int B = 8, S = 512, T = 256, D = 768, H = 12, HID = 3072;
constexpr int V = 50257, O = 64, HD = 64;

typedef short bf16x8 __attribute__((ext_vector_type(8)));
typedef float f32x4 __attribute__((ext_vector_type(4)));

__device__ __forceinline__ float b2f(unsigned short u) {
  union { float f; unsigned v; } x; x.v = ((unsigned)u) << 16; return x.f;
}
__device__ __forceinline__ unsigned short f2b(float f) {
  __hip_bfloat16 h = __float2bfloat16(f);
  return *(unsigned short*)&h;
}

__device__ __forceinline__ void async16(const void* g, void* l) {
  __builtin_amdgcn_global_load_lds(
      (const __attribute__((address_space(1))) void*)g,
      (__attribute__((address_space(3))) void*)l, 16, 0, 0);
}

// ---------------------------------------------------------------------------
// fp32 -> bf16 conversion (8 elems/thread, n % 8 == 0)
// ---------------------------------------------------------------------------
__global__ void cvt_f32_bf16(const float* __restrict__ in,
                             __hip_bfloat16* __restrict__ out, int n) {
  int i = (blockIdx.x * blockDim.x + threadIdx.x) * 8;
  if (i + 8 > n) return;
  float4 v0 = *(const float4*)&in[i];
  float4 v1 = *(const float4*)&in[i + 4];
  ushort4 o0, o1;
  o0.x = f2b(v0.x); o0.y = f2b(v0.y); o0.z = f2b(v0.z); o0.w = f2b(v0.w);
  o1.x = f2b(v1.x); o1.y = f2b(v1.y); o1.z = f2b(v1.z); o1.w = f2b(v1.w);
  *(ushort4*)&out[i] = o0;
  *(ushort4*)&out[i + 4] = o1;
}

// ---------------------------------------------------------------------------
// bf16 MFMA GEMM: C[M,N] = A[M,K] @ W[N,K]^T + bias, optional ReLU.
// BM=128, BN in {64,128}, BK=32. 256 threads = 4 waves (2x2).
// TRANSV: write Cb transposed as vt[(r/512)*768 + c][r%512] (V for attention).
// ---------------------------------------------------------------------------
template <int BN, bool RELU, bool TRANSV>
__global__ __launch_bounds__(256) void gemm_mfma_kernel(
    const __hip_bfloat16* __restrict__ A, const __hip_bfloat16* __restrict__ W,
    const float* __restrict__ bias, float* __restrict__ Cf,
    __hip_bfloat16* __restrict__ Cb, int M, int N, int K) {
  constexpr int BM = 128, BK = 32;
  constexpr int WTN = BN / 2;      // wave tile N: 64 or 32
  constexpr int NFRAG = WTN / 16;  // 4 or 2
  __shared__ __hip_bfloat16 Als[BM * BK];
  __shared__ __hip_bfloat16 Bls[BN * BK];
  const int tid = threadIdx.x;
  const int lane = tid & 63, wid = tid >> 6;
  const int wm = wid >> 1, wn = wid & 1;
  const int row0 = blockIdx.y * BM, col0 = blockIdx.x * BN;
  const int lr = lane & 15;          // frag row/col
  const int ko = (lane >> 4) * 8;    // frag k offset (elems)

  f32x4 acc[4][NFRAG] = {};

  for (int k0 = 0; k0 < K; k0 += BK) {
#pragma unroll
    for (int c = 0; c < 2; ++c) {
      int j = tid + c * 256;
      int r = j >> 2, col = (j & 3) * 8;
      async16(&A[(size_t)(row0 + r) * K + k0 + col], (void*)&Als[j * 8]);
    }
#pragma unroll
    for (int c = 0; c < BN / 64; ++c) {
      int j = tid + c * 256;
      int r = j >> 2, col = (j & 3) * 8;
      async16(&W[(size_t)(col0 + r) * K + k0 + col], (void*)&Bls[j * 8]);
    }
    __syncthreads();

    bf16x8 af[4], bfr[NFRAG];
#pragma unroll
    for (int mi = 0; mi < 4; ++mi)
      af[mi] = *(const bf16x8*)&Als[(wm * 64 + mi * 16 + lr) * BK + ko];
#pragma unroll
    for (int ni = 0; ni < NFRAG; ++ni)
      bfr[ni] = *(const bf16x8*)&Bls[(wn * WTN + ni * 16 + lr) * BK + ko];
#pragma unroll
    for (int mi = 0; mi < 4; ++mi)
#pragma unroll
      for (int ni = 0; ni < NFRAG; ++ni)
        acc[mi][ni] = __builtin_amdgcn_mfma_f32_16x16x32_bf16(
            af[mi], bfr[ni], acc[mi][ni], 0, 0, 0);
    __syncthreads();
  }

#pragma unroll
  for (int mi = 0; mi < 4; ++mi) {
    int rbase = row0 + wm * 64 + mi * 16 + (lane >> 4) * 4;
#pragma unroll
    for (int ni = 0; ni < NFRAG; ++ni) {
      int c = col0 + wn * WTN + ni * 16 + lr;
      float bv = bias[c];
#pragma unroll
      for (int r = 0; r < 4; ++r) {
        float val = acc[mi][ni][r] + bv;
        if (RELU) val = fmaxf(val, 0.f);
        int rr = rbase + r;
        if (TRANSV) {
          // vt[((rr/512)*768 + c)][rr%512]
          size_t idx = (((size_t)(rr >> 9) * D + c) << 9) | (size_t)(rr & 511);
          Cb[idx] = __float2bfloat16(val);
        } else {
          if (Cf) Cf[(size_t)rr * N + c] = val;
          if (Cb) Cb[(size_t)rr * N + c] = __float2bfloat16(val);
        }
      }
    }
  }
}

// ---------------------------------------------------------------------------
// Row softmax over O=64 (one wave per row)
// ---------------------------------------------------------------------------
__global__ void softmax64_kernel(const float* __restrict__ logits,
                                 float* __restrict__ probs, int rows) {
  int row = blockIdx.x * (blockDim.x >> 6) + (threadIdx.x >> 6);
  int lane = threadIdx.x & 63;
  if (row >= rows) return;
  float x = logits[(size_t)row * 64 + lane];
  float m = x;
#pragma unroll
  for (int o = 32; o > 0; o >>= 1) m = fmaxf(m, __shfl_xor(m, o));
  float e = __expf(x - m);
  float ssum = e;
#pragma unroll
  for (int o = 32; o > 0; o >>= 1) ssum += __shfl_xor(ssum, o);
  probs[(size_t)row * 64 + lane] = e / ssum;
}

// ---------------------------------------------------------------------------
// Attention v3 (MFMA): one block (256 thr = 4 waves) per (b, h, 32-t tile).
// q,k normal [row][D] bf16; vt transposed [b][h][d][s] bf16.
// QK^T and PV via mfma_f32_16x16x32_bf16. Scores/P in LDS bf16 [32][520].
// K/Vt staged via global_load_lds with pre-swizzled source (slot ^= row&7).
// P written to global Pg[b][h][t][s] (head-mean done in scatter).
// ---------------------------------------------------------------------------
__global__ __launch_bounds__(256) void attention3_kernel(
    const __hip_bfloat16* __restrict__ q, const __hip_bfloat16* __restrict__ k,
    const __hip_bfloat16* __restrict__ vt, const unsigned char* __restrict__ mask,
    __hip_bfloat16* __restrict__ ctx, __hip_bfloat16* __restrict__ Pg) {
  constexpr int TB = 32;
  constexpr int SCP = 520;  // sc row stride (elems), 16B-aligned rows, 2-way banks
  __shared__ __hip_bfloat16 Qls[TB * 64];     // 4 KB, swizzled
  __shared__ __hip_bfloat16 KVls[128 * 64];   // 16 KB, K chunk or Vt chunk
  __shared__ __hip_bfloat16 sc[TB * SCP];     // 32.5 KB scores/P
  const int tid = threadIdx.x;
  const int lane = tid & 63, w = tid >> 6;
  const int lr = lane & 15, lg = lane >> 4;
  const int bid = blockIdx.x;
  const int tile = bid & 7;            // T/32 = 8
  const int h = (bid >> 3) % H;
  const int b = bid / (8 * H);
  const int t0 = tile * TB;

  // stage Q (32x64): 256 chunks of 16B, source slot pre-swizzled
  {
    int r = tid >> 3, slot = tid & 7;
    int g = slot ^ (r & 7);
    async16(&q[((size_t)(b * T + t0 + r)) * D + h * 64 + g * 8],
            (void*)&Qls[tid * 8]);
  }

  // ---- QK^T: 4 chunks of 128 s ----
  for (int ch = 0; ch < 4; ++ch) {
    const int s0 = ch * 128;
#pragma unroll
    for (int it = 0; it < 4; ++it) {
      int c = tid + it * 256;
      int r = c >> 3, slot = c & 7;
      int g = slot ^ (r & 7);
      async16(&k[((size_t)(b * S + s0 + r)) * D + h * 64 + g * 8],
              (void*)&KVls[c * 8]);
    }
    __syncthreads();
    f32x4 acc[2][2] = {};
#pragma unroll
    for (int ks = 0; ks < 2; ++ks) {
      bf16x8 af[2], bfr[2];
#pragma unroll
      for (int mi = 0; mi < 2; ++mi) {
        int row = mi * 16 + lr;
        int slot = (4 * ks + lg) ^ (row & 7);
        af[mi] = *(const bf16x8*)&Qls[row * 64 + slot * 8];
      }
#pragma unroll
      for (int ni = 0; ni < 2; ++ni) {
        int row = w * 32 + ni * 16 + lr;
        int slot = (4 * ks + lg) ^ (row & 7);
        bfr[ni] = *(const bf16x8*)&KVls[row * 64 + slot * 8];
      }
#pragma unroll
      for (int mi = 0; mi < 2; ++mi)
#pragma unroll
        for (int ni = 0; ni < 2; ++ni)
          acc[mi][ni] = __builtin_amdgcn_mfma_f32_16x16x32_bf16(
              af[mi], bfr[ni], acc[mi][ni], 0, 0, 0);
    }
    // scale + mask + store scores (bf16) to sc
#pragma unroll
    for (int ni = 0; ni < 2; ++ni) {
      int s_local = w * 32 + ni * 16 + lr;
      bool msk = mask[b * S + s0 + s_local];
#pragma unroll
      for (int mi = 0; mi < 2; ++mi) {
        int trow = mi * 16 + lg * 4;
#pragma unroll
        for (int rg = 0; rg < 4; ++rg) {
          float val = msk ? -INFINITY : acc[mi][ni][rg] * 0.125f;
          sc[(trow + rg) * SCP + s0 + s_local] = __float2bfloat16(val);
        }
      }
    }
    __syncthreads();
  }

  // ---- softmax: wave w handles rows w*8 .. w*8+7 ----
  unsigned short* scu = (unsigned short*)sc;
  unsigned short* pgu = (unsigned short*)Pg;
#pragma unroll
  for (int i = 0; i < 8; ++i) {
    int r = w * 8 + i;
    float x[8];
    float m = -INFINITY;
#pragma unroll
    for (int j = 0; j < 8; ++j) {
      x[j] = b2f(scu[r * SCP + j * 64 + lane]);
      m = fmaxf(m, x[j]);
    }
#pragma unroll
    for (int o = 32; o > 0; o >>= 1) m = fmaxf(m, __shfl_xor(m, o));
    float ssum = 0.f;
#pragma unroll
    for (int j = 0; j < 8; ++j) { x[j] = __expf(x[j] - m); ssum += x[j]; }
#pragma unroll
    for (int o = 32; o > 0; o >>= 1) ssum += __shfl_xor(ssum, o);
    float inv = 1.f / ssum;
#pragma unroll
    for (int j = 0; j < 8; ++j) {
      unsigned short pb = f2b(x[j] * inv);
      scu[r * SCP + j * 64 + lane] = pb;
      pgu[(((size_t)(b * H + h)) * T + t0 + r) * S + j * 64 + lane] = pb;
    }
  }
  __syncthreads();

  // ---- PV: wave w owns d range [w*16, w*16+16) ----
  f32x4 accp[2] = {};
  for (int ch = 0; ch < 4; ++ch) {
    const int s0 = ch * 128;
#pragma unroll
    for (int it = 0; it < 4; ++it) {
      int c = tid + it * 256;
      int d = c >> 4, slot = c & 15;
      int g = slot ^ (d & 7);
      async16(&vt[(((size_t)(b * H + h)) * 64 + d) * S + s0 + g * 8],
              (void*)&KVls[c * 8]);
    }
    __syncthreads();
#pragma unroll
    for (int ks = 0; ks < 4; ++ks) {
      bf16x8 bfr;
      {
        int brow = w * 16 + lr;
        int slot = (4 * ks + lg) ^ (brow & 7);
        bfr = *(const bf16x8*)&KVls[brow * 128 + slot * 8];
      }
#pragma unroll
      for (int mi = 0; mi < 2; ++mi) {
        int prow = mi * 16 + lr;
        bf16x8 af = *(const bf16x8*)&sc[prow * SCP + s0 + ks * 32 + lg * 8];
        accp[mi] = __builtin_amdgcn_mfma_f32_16x16x32_bf16(af, bfr, accp[mi], 0, 0, 0);
      }
    }
    __syncthreads();
  }
  // epilogue: ctx[b*T + t][h*64 + d]
#pragma unroll
  for (int mi = 0; mi < 2; ++mi) {
    int trow = mi * 16 + lg * 4;
#pragma unroll
    for (int rg = 0; rg < 4; ++rg) {
      ctx[((size_t)(b * T + t0 + trow + rg)) * D + h * 64 + w * 16 + lr] =
          __float2bfloat16(accp[mi][rg]);
    }
  }
}

// ---------------------------------------------------------------------------
// Copy head: sigmoid(context_out @ copy_w + copy_b), one wave per row
// ---------------------------------------------------------------------------
__global__ void copy_head_kernel(const float* __restrict__ co,
                                 const float* __restrict__ w,
                                 const float* __restrict__ bptr,
                                 float* __restrict__ cp, int rows) {
  int row = blockIdx.x * (blockDim.x >> 6) + (threadIdx.x >> 6);
  int lane = threadIdx.x & 63;
  if (row >= rows) return;
  float acc = 0.f;
#pragma unroll
  for (int d = lane; d < D; d += 64) acc += co[(size_t)row * D + d] * w[d];
#pragma unroll
  for (int o = 32; o > 0; o >>= 1) acc += __shfl_xor(acc, o);
  if (lane == 0) cp[row] = 1.f / (1.f + __expf(-(acc + bptr[0])));
}

// ---------------------------------------------------------------------------
// Scatter: head-mean of Pg + copy gate, atomically into out (pre-zeroed)
// ---------------------------------------------------------------------------
__global__ void scatter2_kernel(const int* __restrict__ src,
                                const int* __restrict__ onto,
                                const __hip_bfloat16* __restrict__ Pg,
                                const float* __restrict__ op,
                                const float* __restrict__ cp,
                                float* __restrict__ out) {
  long long i = (long long)blockIdx.x * blockDim.x + threadIdx.x;
  const long long nsrc = (long long)B * T * S;
  const long long nonto = (long long)B * T * O;
  if (i < nsrc) {
    int s = (int)(i & (S - 1));
    int bt = (int)(i >> 9);
    int b = bt >> 8;
    int t = bt & (T - 1);
    const unsigned short* pg = (const unsigned short*)Pg;
    float sum = 0.f;
#pragma unroll
    for (int h = 0; h < H; ++h)
      sum += b2f(pg[(((size_t)(b * H + h)) * T + t) * S + s]);
    float val = sum * (1.0f / (float)H) * cp[bt];
    atomicAdd(&out[(size_t)bt * V + src[b * S + s]], val);
  } else if (i < nsrc + nonto) {
    long long j = i - nsrc;
    int o = (int)(j % O);
    long long bt = j / O;
    float val = op[j] * (1.f - cp[bt]);
    atomicAdd(&out[bt * V + onto[o]], val);
  }
}

// ---------------------------------------------------------------------------
extern "C" void kernel_launch(void* const* d_in, const int* in_sizes, int n_in,
                              void* d_out, int out_size, void* d_ws, size_t ws_size,
                              hipStream_t stream) {
  const int* src_ids = (const int*)d_in[0];
  const float* enc = (const float*)d_in[1];
  const unsigned char* mask = (const unsigned char*)d_in[2];
  const float* dec = (const float*)d_in[3];
  const int* onto_ids = (const int*)d_in[4];
  const float* Wq = (const float*)d_in[5];
  const float* bq = (const float*)d_in[6];
  const float* Wk = (const float*)d_in[7];
  const float* bk = (const float*)d_in[8];
  const float* Wv = (const float*)d_in[9];
  const float* bv = (const float*)d_in[10];
  const float* Wo = (const float*)d_in[11];
  const float* bo = (const float*)d_in[12];
  const float* copy_w = (const float*)d_in[13];
  const float* copy_b = (const float*)d_in[14];
  const float* W1 = (const float*)d_in[15];
  const float* b1 = (const float*)d_in[16];
  const float* W2 = (const float*)d_in[17];
  const float* b2 = (const float*)d_in[18];

  const int MT = B * T;   // 2048
  const int MS = B * S;   // 4096

  // bf16 workspace
  __hip_bfloat16* wb = (__hip_bfloat16*)d_ws;
  __hip_bfloat16* qb16 = wb;    wb += (size_t)MT * D;
  __hip_bfloat16* kb16 = wb;    wb += (size_t)MS * D;
  __hip_bfloat16* vt = wb;      wb += (size_t)MS * D;   // [b][h][d][s]
  __hip_bfloat16* ctxb16 = wb;  wb += (size_t)MT * D;
  __hip_bfloat16* W2b = wb;     wb += (size_t)O * HID;
  __hip_bfloat16* Wqb = wb;     wb += (size_t)D * D;
  __hip_bfloat16* Wkb = wb;     wb += (size_t)D * D;
  __hip_bfloat16* Wvb = wb;     wb += (size_t)D * D;
  __hip_bfloat16* Wob = wb;     wb += (size_t)D * D;
  // alias region: Pg [B,H,T,S] (12.58M elems) overlays decb/encb/W1b/hb16
  // (13.37M elems) — all consumers of the latter finish before attention3.
  __hip_bfloat16* Pg = wb;
  __hip_bfloat16* decb = wb;    wb += (size_t)MT * D;
  __hip_bfloat16* encb = wb;    wb += (size_t)MS * D;
  __hip_bfloat16* W1b = wb;     wb += (size_t)HID * D;
  __hip_bfloat16* hb16 = wb;    wb += (size_t)MT * HID;
  // fp32 workspace
  float* wf = (float*)wb;
  float* logits = wf;           wf += (size_t)MT * O;
  float* ontop = wf;            wf += (size_t)MT * O;
  float* ctxout = wf;           wf += (size_t)MT * D;
  float* cp = wf;               wf += (size_t)MT;

  float* out = (float*)d_out;

  hipMemsetAsync(out, 0, (size_t)B * T * V * sizeof(float), stream);

  auto cvt = [&](const float* s, __hip_bfloat16* dst, int n) {
    cvt_f32_bf16<<<(n / 8 + 255) / 256, 256, 0, stream>>>(s, dst, n);
  };
  cvt(dec, decb, MT * D);
  cvt(enc, encb, MS * D);
  cvt(W1, W1b, HID * D);
  cvt(W2, W2b, O * HID);
  cvt(Wq, Wqb, D * D);
  cvt(Wk, Wkb, D * D);
  cvt(Wv, Wvb, D * D);
  cvt(Wo, Wob, D * D);

  // Projections (V written transposed for attention)
  gemm_mfma_kernel<128, false, false><<<dim3(D / 128, MT / 128), 256, 0, stream>>>(
      decb, Wqb, bq, nullptr, qb16, MT, D, D);
  gemm_mfma_kernel<128, false, false><<<dim3(D / 128, MS / 128), 256, 0, stream>>>(
      encb, Wkb, bk, nullptr, kb16, MS, D, D);
  gemm_mfma_kernel<128, false, true><<<dim3(D / 128, MS / 128), 256, 0, stream>>>(
      encb, Wvb, bv, nullptr, vt, MS, D, D);

  // Generator FFN
  gemm_mfma_kernel<128, true, false><<<dim3(HID / 128, MT / 128), 256, 0, stream>>>(
      decb, W1b, b1, nullptr, hb16, MT, HID, D);
  gemm_mfma_kernel<64, false, false><<<dim3(1, MT / 128), 256, 0, stream>>>(
      hb16, W2b, b2, logits, nullptr, MT, O, HID);
  softmax64_kernel<<<MT / 4, 256, 0, stream>>>(logits, ontop, MT);

  // Attention (after FFN2: Pg alias region is dead from here on)
  attention3_kernel<<<B * H * (T / 32), 256, 0, stream>>>(
      qb16, kb16, vt, mask, ctxb16, Pg);

  // Output projection + copy head
  gemm_mfma_kernel<128, false, false><<<dim3(D / 128, MT / 128), 256, 0, stream>>>(
      ctxb16, Wob, bo, ctxout, nullptr, MT, D, D);
  copy_head_kernel<<<MT / 4, 256, 0, stream>>>(ctxout, copy_w, copy_b, cp, MT);

  // Scatter
  long long total = (long long)B * T * (S + O);
  int nblk = (int)((total + 255) / 256);
  scatter2_kernel<<<nblk, 256, 0, stream>>>(src_ids, onto_ids, Pg, ontop, cp, out);
}